// Round 7
// baseline (603.982 us; speedup 1.0000x reference)
//
#include <hip/hip_runtime.h>
#include <hip/hip_bf16.h>

typedef unsigned short u16;
typedef unsigned int u32;

using bf16x8 = __attribute__((ext_vector_type(8))) short;
using f32x4  = __attribute__((ext_vector_type(4))) float;

static constexpr int TOK  = 8192;   // BS*L
static constexpr int SEQ  = 2048;
static constexpr int DM   = 1024;
static constexpr int FF   = 4096;
static constexpr int NE   = 8;
static constexpr int MAXT = 72;     // 128-row M-tiles: 8192/128 + 8 remainders
static constexpr int KS2  = 4;      // split-K for ffn2
static constexpr int NWG1 = MAXT * (FF/128);         // 2304, %8==0
static constexpr int NWG2 = MAXT * (DM/128) * KS2;   // 2304, %8==0

// ---- workspace layout (bytes) ----
static constexpr size_t O_LOGITS = 0;                                  // 8192*8*4
static constexpr size_t O_M      = 262144;
static constexpr size_t O_Z      = O_M + 128;
static constexpr size_t O_CNT    = O_Z + 128;
static constexpr size_t O_CUR    = O_CNT + 64;
static constexpr size_t O_OFF    = O_CUR + 64;
static constexpr size_t O_DESC   = 263168;                            // 72 * int4
static constexpr size_t O_PERM   = 266240;                            // 8192 i32
static constexpr size_t O_IDX    = 299008;                            // 8192 i32
static constexpr size_t O_XG     = 524288;                            // 16 MB bf16
static constexpr size_t O_W1T    = O_XG  + (size_t)TOK*DM*2;          // 64 MB bf16 [e][f][d]
static constexpr size_t O_W2T    = O_W1T + (size_t)NE*DM*FF*2;        // 64 MB bf16 [e][d][f]
static constexpr size_t O_H      = O_W2T + (size_t)NE*DM*FF*2;        // 64 MB bf16 [pos][f]

__device__ __forceinline__ u16 f2bf(float f){
  __hip_bfloat16 h = __float2bfloat16(f);
  return *reinterpret_cast<u16*>(&h);
}

__device__ __forceinline__ void gld_lds16(const void* g, void* l){
  __builtin_amdgcn_global_load_lds((const __attribute__((address_space(1))) void*)g,
                                   (__attribute__((address_space(3))) void*)l, 16, 0, 0);
}

// cheap GELU: tanh-form, |err vs erf-form| < ~3e-3 (validated R2-R6, absmax 0.0156)
__device__ __forceinline__ float gelu_f(float v){
  float u = v * fmaf(v*v, 0.044715f, 1.0f) * 0.7978845608f;
  float ex = __builtin_amdgcn_exp2f(u * -2.885390082f);   // exp(-2u)
  return v * __builtin_amdgcn_rcpf(1.0f + ex);
}

// ---- 1) gate logits ----
__global__ void k_gate(const float* __restrict__ x, const float* __restrict__ gw,
                       const float* __restrict__ gb, float* __restrict__ logits){
  __shared__ float sgw[NE*DM];                 // [e][d]
  for (int i = threadIdx.x; i < DM*NE; i += 256){
    int d = i >> 3, e = i & 7;                 // gw is [d][e]
    sgw[e*DM + d] = gw[i];
  }
  __syncthreads();
  int wave = threadIdx.x >> 6, lane = threadIdx.x & 63;
  int t = blockIdx.x * 4 + wave;
  const float4* xr = (const float4*)(x + (size_t)t * DM);
  float acc[NE];
#pragma unroll
  for (int e = 0; e < NE; ++e) acc[e] = 0.f;
#pragma unroll
  for (int k = 0; k < 4; ++k){
    int v4 = k*64 + lane;
    float4 v = xr[v4];
#pragma unroll
    for (int e = 0; e < NE; ++e){
      const float4 g = *(const float4*)&sgw[e*DM + v4*4];
      acc[e] = fmaf(v.x, g.x, fmaf(v.y, g.y, fmaf(v.z, g.z, fmaf(v.w, g.w, acc[e]))));
    }
  }
#pragma unroll
  for (int off = 32; off; off >>= 1)
#pragma unroll
    for (int e = 0; e < NE; ++e) acc[e] += __shfl_xor(acc[e], off);
  if (lane == 0){
#pragma unroll
    for (int e = 0; e < NE; ++e) logits[(size_t)t*NE + e] = acc[e] + gb[e];
  }
}

// ---- 2) per (b,e): max and sum(exp) over seq ----
__global__ void k_lse(const float* __restrict__ logits, float* __restrict__ mOut,
                      float* __restrict__ zOut){
  int be = blockIdx.x;
  int b = be >> 3, e = be & 7;
  const float* base = logits + ((size_t)b*SEQ)*NE + e;
  float m = -INFINITY;
  for (int l = threadIdx.x; l < SEQ; l += 256) m = fmaxf(m, base[(size_t)l*NE]);
  __shared__ float red[8];
#pragma unroll
  for (int off = 32; off; off >>= 1) m = fmaxf(m, __shfl_xor(m, off));
  if ((threadIdx.x & 63) == 0) red[threadIdx.x >> 6] = m;
  __syncthreads();
  m = fmaxf(fmaxf(red[0], red[1]), fmaxf(red[2], red[3]));
  float s = 0.f;
  for (int l = threadIdx.x; l < SEQ; l += 256) s += expf(base[(size_t)l*NE] - m);
#pragma unroll
  for (int off = 32; off; off >>= 1) s += __shfl_xor(s, off);
  if ((threadIdx.x & 63) == 0) red[4 + (threadIdx.x >> 6)] = s;
  __syncthreads();
  if (threadIdx.x == 0){ mOut[be] = m; zOut[be] = red[4]+red[5]+red[6]+red[7]; }
}

// ---- 3) route ----
__global__ void k_route(const float* __restrict__ logits, const float* __restrict__ m,
                        const float* __restrict__ z, u32* __restrict__ cnt,
                        int* __restrict__ idx){
  int t = blockIdx.x*256 + threadIdx.x;
  int b = t >> 11;
  const float* lr = logits + (size_t)t*NE;
  float best = -INFINITY; int be = 0;
#pragma unroll
  for (int e = 0; e < NE; ++e){
    float p = expf(lr[e] - m[b*NE + e]) / z[b*NE + e];
    if (p > best){ best = p; be = e; }
  }
  idx[t] = be;
  atomicAdd(&cnt[be], 1u);
}

// ---- 4) plan ----
__global__ void k_plan(const u32* __restrict__ cnt, int* __restrict__ off,
                       int4* __restrict__ desc, u32* __restrict__ cur){
  if (threadIdx.x == 0){
    int offs[NE+1]; int o = 0;
    for (int e = 0; e < NE; ++e){ offs[e] = o; o += (int)cnt[e]; }
    offs[NE] = o;
    int nt = 0;
    for (int e = 0; e < NE; ++e){
      int c = (int)cnt[e];
      for (int s = 0; s < c; s += 128)
        desc[nt++] = make_int4(e, offs[e] + s, min(128, c - s), 0);
      off[e] = offs[e]; cur[e] = 0u;
    }
    off[NE] = offs[NE];
    for (int i = nt; i < MAXT; ++i) desc[i] = make_int4(-1, 0, 0, 0);
  }
}

// ---- 5) scatter ----
__global__ void k_scatter(const int* __restrict__ idx, const int* __restrict__ off,
                          u32* __restrict__ cur, int* __restrict__ perm){
  int t = blockIdx.x*256 + threadIdx.x;
  int e = idx[t];
  int pos = off[e] + (int)atomicAdd(&cur[e], 1u);
  perm[pos] = t;
}

// ---- 6) gather x rows -> bf16, fused bias-init of out ----
__global__ void k_gather(const float* __restrict__ x, const int* __restrict__ perm,
                         const int* __restrict__ idx, const float* __restrict__ b2,
                         u16* __restrict__ Xg, float* __restrict__ out){
  int p = blockIdx.x;
  int t = perm[p];
  int e = idx[t];
  const float4* src = (const float4*)(x + (size_t)t*DM);
  float4 v = src[threadIdx.x];
  uint2 o;
  o.x = (u32)f2bf(v.x) | ((u32)f2bf(v.y) << 16);
  o.y = (u32)f2bf(v.z) | ((u32)f2bf(v.w) << 16);
  *(uint2*)(Xg + (size_t)p*DM + threadIdx.x*4) = o;
  float4 bv = ((const float4*)(b2 + (size_t)e*DM))[threadIdx.x];
  ((float4*)(out + (size_t)t*DM))[threadIdx.x] = bv;
}

// ---- 7) transpose+convert weights fp32 [E][R][C] -> bf16 [E][C][R] ----
__global__ void k_trans(const float* __restrict__ in, u16* __restrict__ out,
                        int R, int C){
  __shared__ float tile[64][65];
  int e = blockIdx.z;
  int r0 = blockIdx.x*64, c0 = blockIdx.y*64;
  const float* src = in + ((size_t)e*R + r0)*C + c0;
  int lr = threadIdx.x >> 4, lc = (threadIdx.x & 15) * 4;
#pragma unroll
  for (int i = 0; i < 4; ++i){
    float4 v = *(const float4*)(src + (size_t)(lr + i*16)*C + lc);
    tile[lr + i*16][lc+0] = v.x; tile[lr + i*16][lc+1] = v.y;
    tile[lr + i*16][lc+2] = v.z; tile[lr + i*16][lc+3] = v.w;
  }
  __syncthreads();
  u16* dst = out + ((size_t)e*C + c0)*R + r0;
#pragma unroll
  for (int i = 0; i < 4; ++i){
    int oc = lr + i*16;
    u16 a0 = f2bf(tile[lc+0][oc]);
    u16 a1 = f2bf(tile[lc+1][oc]);
    u16 a2 = f2bf(tile[lc+2][oc]);
    u16 a3 = f2bf(tile[lc+3][oc]);
    uint2 o; o.x = (u32)a0 | ((u32)a1 << 16); o.y = (u32)a2 | ((u32)a3 << 16);
    *(uint2*)(dst + (size_t)oc*R + lc) = o;
  }
}

// ======== B-direct-streaming GEMM: 128x128, 4 waves, BK=64, KT=16 ========
// A: triple-buffered LDS (48 KB), staged 2 K-tiles ahead via global_load_lds,
//    T2 XOR swizzle (proven 0-conflict R3-R5). B: straight global->reg b128
//    fragments from the L2-resident panel (no LDS, no barrier coupling).
// ONE __builtin_amdgcn_s_barrier() per K-tile, NO memory-clobbered asm (R4/R5
// lesson: "memory" clobber forced compiler vmcnt(0) drains -> all schedules
// degenerated to drain-0). Compiler's register-dep waits for b implicitly
// drain S(kt) (issue order ... B(kt-1), S(kt+1), B(kt), S(kt+2): waiting the
// newest b leaves only newer stage-loads outstanding) -> counted pipeline.

// ---- 8) grouped GEMM 1: H = gelu(Xg @ W1T^T + b1) ----
__global__ __launch_bounds__(256, 3) void k_ffn1(const u16* __restrict__ Xg,
    const u16* __restrict__ W1T, const float* __restrict__ b1,
    u16* __restrict__ H, const int4* __restrict__ desc){
  int pid = blockIdx.x;                        // NWG1 = 2304
  int pid_sw = (pid & 7) * (NWG1/8) + (pid >> 3);
  int ng  = pid_sw / (MAXT*8);                 // n-group 0..3
  int rem = pid_sw - ng*(MAXT*8);
  int mt  = rem >> 3;
  int n0  = (ng*8 + (rem & 7)) * 128;
  int4 dd = desc[mt];
  int e = dd.x; if (e < 0) return;
  int m0 = dd.y, valid = dd.z;

  __shared__ __align__(16) u16 lA[3][128*64];  // 48 KiB

  int tid = threadIdx.x, lane = tid & 63, wave = tid >> 6;
  int wr = wave >> 1, wc = wave & 1;
  const u16* Bsrc = W1T + ((size_t)e*FF + n0)*DM;

  f32x4 acc[4][4] = {};
  bf16x8 a[4][2], b[4][2];

  int srow = lane >> 3;                        // 0..7
  int cole = ((lane & 7) ^ srow) << 3;         // inverse-swizzled k-elem offset

  const u16* rowp[4];
#pragma unroll
  for (int g = 0; g < 4; ++g)
    rowp[g] = Bsrc + (size_t)(wc*64 + g*16 + (lane & 15))*DM + (lane >> 4)*8;

  auto STAGE = [&](int buf, int kt){
    int k0 = kt * 64;
    char* dA = (char*)&lA[buf][0];
#pragma unroll
    for (int c = 0; c < 4; ++c){
      int ci = wave*4 + c;                     // 16 chunks of 1 KiB = 8 rows
      int row = ci*8 + srow;
      int ra = m0 + row; if (ra > TOK-1) ra = TOK-1;
      gld_lds16(Xg + (size_t)ra*DM + k0 + cole, dA + ci*1024);
    }
  };
  auto LDB = [&](int kt){
#pragma unroll
    for (int g = 0; g < 4; ++g){
      b[g][0] = *(const bf16x8*)(rowp[g] + kt*64);
      b[g][1] = *(const bf16x8*)(rowp[g] + kt*64 + 32);
    }
  };
  auto LDA = [&](const u16* tb){
#pragma unroll
    for (int f = 0; f < 4; ++f){
      int R = wr*64 + f*16 + (lane & 15);
      int base = R*128 + (((lane >> 4)*16) ^ ((R & 7) << 4));
      a[f][0] = *(const bf16x8*)((const char*)tb + base);
      a[f][1] = *(const bf16x8*)((const char*)tb + (base ^ 64));
    }
  };

  STAGE(0, 0);
  STAGE(1, 1);
  asm volatile("s_waitcnt vmcnt(4)");          // buf0 landed; buf1 in flight
  __builtin_amdgcn_sched_barrier(0);
  const int KT = DM / 64;                      // 16
  for (int kt = 0; kt < KT; ++kt){
    __builtin_amdgcn_s_barrier();              // buf[kt%3] ready; prev reads retired
    LDB(kt);                                   // B frags global->reg (L2)
    if (kt + 2 < KT) STAGE((kt + 2) % 3, kt + 2);
    LDA(&lA[kt % 3][0]);                       // 8 swizzled ds_read_b128
    __builtin_amdgcn_s_setprio(1);
#pragma unroll
    for (int m = 0; m < 4; ++m)
#pragma unroll
      for (int n = 0; n < 4; ++n){
        acc[m][n] = __builtin_amdgcn_mfma_f32_16x16x32_bf16(a[m][0], b[n][0], acc[m][n], 0,0,0);
        acc[m][n] = __builtin_amdgcn_mfma_f32_16x16x32_bf16(a[m][1], b[n][1], acc[m][n], 0,0,0);
      }
    __builtin_amdgcn_s_setprio(0);
  }

#pragma unroll
  for (int n = 0; n < 4; ++n){
    int col = n0 + wc*64 + n*16 + (lane & 15);
    float bias = b1[(size_t)e*FF + col];
#pragma unroll
    for (int m = 0; m < 4; ++m){
      int rbase = wr*64 + m*16 + ((lane >> 4) << 2);
#pragma unroll
      for (int j = 0; j < 4; ++j){
        int rit = rbase + j;
        if (rit < valid){
          float v = acc[m][n][j] + bias;
          H[(size_t)(m0 + rit)*FF + col] = f2bf(gelu_f(v));
        }
      }
    }
  }
}

// ---- 9) grouped GEMM 2: out[tok] += H @ W2T^T (split-K=4, atomic f32) ----
__global__ __launch_bounds__(256, 3) void k_ffn2(const u16* __restrict__ H,
    const u16* __restrict__ W2T, float* __restrict__ out,
    const int4* __restrict__ desc, const int* __restrict__ perm){
  int pid = blockIdx.x;                        // NWG2 = 2304
  int pid_sw = (pid & 7) * (NWG2/8) + (pid >> 3);
  int ks  = pid_sw / (MAXT*8);                 // k-split outer (chunk in one stripe)
  int rem = pid_sw - ks*(MAXT*8);
  int mt  = rem >> 3;
  int n0  = (rem & 7) * 128;
  int4 dd = desc[mt];
  int e = dd.x; if (e < 0) return;
  int m0 = dd.y, valid = dd.z;

  __shared__ __align__(16) u16 lA[3][128*64];  // 48 KiB

  int tid = threadIdx.x, lane = tid & 63, wave = tid >> 6;
  int wr = wave >> 1, wc = wave & 1;
  const u16* Bsrc = W2T + ((size_t)e*DM + n0)*FF;
  const int kbase = ks * (FF/KS2);             // 1024 elems per split

  f32x4 acc[4][4] = {};
  bf16x8 a[4][2], b[4][2];

  int srow = lane >> 3;
  int cole = ((lane & 7) ^ srow) << 3;

  const u16* rowp[4];
#pragma unroll
  for (int g = 0; g < 4; ++g)
    rowp[g] = Bsrc + (size_t)(wc*64 + g*16 + (lane & 15))*FF + kbase + (lane >> 4)*8;

  auto STAGE = [&](int buf, int kt){
    int k0 = kbase + kt * 64;
    char* dA = (char*)&lA[buf][0];
#pragma unroll
    for (int c = 0; c < 4; ++c){
      int ci = wave*4 + c;
      int row = ci*8 + srow;
      int ra = m0 + row; if (ra > TOK-1) ra = TOK-1;
      gld_lds16(H + (size_t)ra*FF + k0 + cole, dA + ci*1024);
    }
  };
  auto LDB = [&](int kt){
#pragma unroll
    for (int g = 0; g < 4; ++g){
      b[g][0] = *(const bf16x8*)(rowp[g] + kt*64);
      b[g][1] = *(const bf16x8*)(rowp[g] + kt*64 + 32);
    }
  };
  auto LDA = [&](const u16* tb){
#pragma unroll
    for (int f = 0; f < 4; ++f){
      int R = wr*64 + f*16 + (lane & 15);
      int base = R*128 + (((lane >> 4)*16) ^ ((R & 7) << 4));
      a[f][0] = *(const bf16x8*)((const char*)tb + base);
      a[f][1] = *(const bf16x8*)((const char*)tb + (base ^ 64));
    }
  };

  STAGE(0, 0);
  STAGE(1, 1);
  asm volatile("s_waitcnt vmcnt(4)");
  __builtin_amdgcn_sched_barrier(0);
  const int KT = (FF/KS2) / 64;                // 16
  for (int kt = 0; kt < KT; ++kt){
    __builtin_amdgcn_s_barrier();
    LDB(kt);
    if (kt + 2 < KT) STAGE((kt + 2) % 3, kt + 2);
    LDA(&lA[kt % 3][0]);
    __builtin_amdgcn_s_setprio(1);
#pragma unroll
    for (int m = 0; m < 4; ++m)
#pragma unroll
      for (int n = 0; n < 4; ++n){
        acc[m][n] = __builtin_amdgcn_mfma_f32_16x16x32_bf16(a[m][0], b[n][0], acc[m][n], 0,0,0);
        acc[m][n] = __builtin_amdgcn_mfma_f32_16x16x32_bf16(a[m][1], b[n][1], acc[m][n], 0,0,0);
      }
    __builtin_amdgcn_s_setprio(0);
  }

#pragma unroll
  for (int m = 0; m < 4; ++m){
#pragma unroll
    for (int j = 0; j < 4; ++j){
      int rit = wr*64 + m*16 + ((lane >> 4) << 2) + j;
      if (rit < valid){
        int tok = perm[m0 + rit];
#pragma unroll
        for (int n = 0; n < 4; ++n){
          int col = n0 + wc*64 + n*16 + (lane & 15);
          unsafeAtomicAdd(&out[(size_t)tok*DM + col], acc[m][n][j]);
        }
      }
    }
  }
}

extern "C" void kernel_launch(void* const* d_in, const int* in_sizes, int n_in,
                              void* d_out, int out_size, void* d_ws, size_t ws_size,
                              hipStream_t stream){
  const float* x   = (const float*)d_in[0];
  const float* gw  = (const float*)d_in[1];
  const float* gb  = (const float*)d_in[2];
  const float* W1  = (const float*)d_in[3];
  const float* b1  = (const float*)d_in[4];
  const float* W2  = (const float*)d_in[5];
  const float* b2  = (const float*)d_in[6];
  float* out = (float*)d_out;
  char* ws = (char*)d_ws;

  float* logits = (float*)(ws + O_LOGITS);
  float* mArr   = (float*)(ws + O_M);
  float* zArr   = (float*)(ws + O_Z);
  u32*   cnt    = (u32*)  (ws + O_CNT);
  u32*   cur    = (u32*)  (ws + O_CUR);
  int*   off    = (int*)  (ws + O_OFF);
  int4*  desc   = (int4*) (ws + O_DESC);
  int*   perm   = (int*)  (ws + O_PERM);
  int*   idx    = (int*)  (ws + O_IDX);
  u16*   Xg     = (u16*)  (ws + O_XG);
  u16*   W1T    = (u16*)  (ws + O_W1T);
  u16*   W2T    = (u16*)  (ws + O_W2T);
  u16*   Hbuf   = (u16*)  (ws + O_H);

  hipMemsetAsync(ws + O_CNT, 0, 128, stream);   // cnt + cur

  k_gate   <<<TOK/4, 256, 0, stream>>>(x, gw, gb, logits);
  k_lse    <<<32,    256, 0, stream>>>(logits, mArr, zArr);
  k_route  <<<TOK/256, 256, 0, stream>>>(logits, mArr, zArr, cnt, idx);
  k_plan   <<<1,     64,  0, stream>>>(cnt, off, desc, cur);
  k_scatter<<<TOK/256, 256, 0, stream>>>(idx, off, cur, perm);
  k_gather <<<TOK,   256, 0, stream>>>(x, perm, idx, b2, Xg, out);
  k_trans  <<<dim3(DM/64, FF/64, NE), 256, 0, stream>>>(W1, W1T, DM, FF);
  k_trans  <<<dim3(FF/64, DM/64, NE), 256, 0, stream>>>(W2, W2T, FF, DM);
  k_ffn1   <<<NWG1,  256, 0, stream>>>(Xg, W1T, b1, Hbuf, desc);
  k_ffn2   <<<NWG2,  256, 0, stream>>>(Hbuf, W2T, out, desc, perm);
}

// Round 8
// 482.938 us; speedup vs baseline: 1.2506x; 1.2506x over previous
//
#include <hip/hip_runtime.h>
#include <hip/hip_bf16.h>

typedef unsigned short u16;
typedef unsigned int u32;

using bf16x8 = __attribute__((ext_vector_type(8))) short;
using f32x4  = __attribute__((ext_vector_type(4))) float;

static constexpr int TOK  = 8192;   // BS*L
static constexpr int SEQ  = 2048;
static constexpr int DM   = 1024;
static constexpr int FF   = 4096;
static constexpr int NE   = 8;
static constexpr int MAXT = 72;     // 128-row M-tiles: 8192/128 + 8 remainders
static constexpr int KS2  = 4;      // split-K for ffn2
static constexpr int NWG1 = MAXT * (FF/128);         // 2304, %8==0
static constexpr int NWG2 = MAXT * (DM/128) * KS2;   // 2304, %8==0

// ---- workspace layout (bytes) ----
static constexpr size_t O_LOGITS = 0;                                  // 8192*8*4
static constexpr size_t O_M      = 262144;
static constexpr size_t O_Z      = O_M + 128;
static constexpr size_t O_CNT    = O_Z + 128;
static constexpr size_t O_CUR    = O_CNT + 64;
static constexpr size_t O_OFF    = O_CUR + 64;
static constexpr size_t O_DESC   = 263168;                            // 72 * int4
static constexpr size_t O_PERM   = 266240;                            // 8192 i32
static constexpr size_t O_IDX    = 299008;                            // 8192 i32
static constexpr size_t O_XG     = 524288;                            // 16 MB bf16
static constexpr size_t O_W1T    = O_XG  + (size_t)TOK*DM*2;          // 64 MB bf16 [e][f][d]
static constexpr size_t O_W2T    = O_W1T + (size_t)NE*DM*FF*2;        // 64 MB bf16 [e][d][f]
static constexpr size_t O_H      = O_W2T + (size_t)NE*DM*FF*2;        // 64 MB bf16 [pos][f]

__device__ __forceinline__ u16 f2bf(float f){
  __hip_bfloat16 h = __float2bfloat16(f);
  return *reinterpret_cast<u16*>(&h);
}

__device__ __forceinline__ void gld_lds16(const void* g, void* l){
  __builtin_amdgcn_global_load_lds((const __attribute__((address_space(1))) void*)g,
                                   (__attribute__((address_space(3))) void*)l, 16, 0, 0);
}

// cheap GELU: tanh-form, |err vs erf-form| < ~3e-3 (validated R2-R7, absmax 0.0156)
__device__ __forceinline__ float gelu_f(float v){
  float u = v * fmaf(v*v, 0.044715f, 1.0f) * 0.7978845608f;
  float ex = __builtin_amdgcn_exp2f(u * -2.885390082f);   // exp(-2u)
  return v * __builtin_amdgcn_rcpf(1.0f + ex);
}

// ---- 1) gate logits ----
__global__ void k_gate(const float* __restrict__ x, const float* __restrict__ gw,
                       const float* __restrict__ gb, float* __restrict__ logits){
  __shared__ float sgw[NE*DM];                 // [e][d]
  for (int i = threadIdx.x; i < DM*NE; i += 256){
    int d = i >> 3, e = i & 7;                 // gw is [d][e]
    sgw[e*DM + d] = gw[i];
  }
  __syncthreads();
  int wave = threadIdx.x >> 6, lane = threadIdx.x & 63;
  int t = blockIdx.x * 4 + wave;
  const float4* xr = (const float4*)(x + (size_t)t * DM);
  float acc[NE];
#pragma unroll
  for (int e = 0; e < NE; ++e) acc[e] = 0.f;
#pragma unroll
  for (int k = 0; k < 4; ++k){
    int v4 = k*64 + lane;
    float4 v = xr[v4];
#pragma unroll
    for (int e = 0; e < NE; ++e){
      const float4 g = *(const float4*)&sgw[e*DM + v4*4];
      acc[e] = fmaf(v.x, g.x, fmaf(v.y, g.y, fmaf(v.z, g.z, fmaf(v.w, g.w, acc[e]))));
    }
  }
#pragma unroll
  for (int off = 32; off; off >>= 1)
#pragma unroll
    for (int e = 0; e < NE; ++e) acc[e] += __shfl_xor(acc[e], off);
  if (lane == 0){
#pragma unroll
    for (int e = 0; e < NE; ++e) logits[(size_t)t*NE + e] = acc[e] + gb[e];
  }
}

// ---- 2) per (b,e): max and sum(exp) over seq ----
__global__ void k_lse(const float* __restrict__ logits, float* __restrict__ mOut,
                      float* __restrict__ zOut){
  int be = blockIdx.x;
  int b = be >> 3, e = be & 7;
  const float* base = logits + ((size_t)b*SEQ)*NE + e;
  float m = -INFINITY;
  for (int l = threadIdx.x; l < SEQ; l += 256) m = fmaxf(m, base[(size_t)l*NE]);
  __shared__ float red[8];
#pragma unroll
  for (int off = 32; off; off >>= 1) m = fmaxf(m, __shfl_xor(m, off));
  if ((threadIdx.x & 63) == 0) red[threadIdx.x >> 6] = m;
  __syncthreads();
  m = fmaxf(fmaxf(red[0], red[1]), fmaxf(red[2], red[3]));
  float s = 0.f;
  for (int l = threadIdx.x; l < SEQ; l += 256) s += expf(base[(size_t)l*NE] - m);
#pragma unroll
  for (int off = 32; off; off >>= 1) s += __shfl_xor(s, off);
  if ((threadIdx.x & 63) == 0) red[4 + (threadIdx.x >> 6)] = s;
  __syncthreads();
  if (threadIdx.x == 0){ mOut[be] = m; zOut[be] = red[4]+red[5]+red[6]+red[7]; }
}

// ---- 3) route ----
__global__ void k_route(const float* __restrict__ logits, const float* __restrict__ m,
                        const float* __restrict__ z, u32* __restrict__ cnt,
                        int* __restrict__ idx){
  int t = blockIdx.x*256 + threadIdx.x;
  int b = t >> 11;
  const float* lr = logits + (size_t)t*NE;
  float best = -INFINITY; int be = 0;
#pragma unroll
  for (int e = 0; e < NE; ++e){
    float p = expf(lr[e] - m[b*NE + e]) / z[b*NE + e];
    if (p > best){ best = p; be = e; }
  }
  idx[t] = be;
  atomicAdd(&cnt[be], 1u);
}

// ---- 4) plan ----
__global__ void k_plan(const u32* __restrict__ cnt, int* __restrict__ off,
                       int4* __restrict__ desc, u32* __restrict__ cur){
  if (threadIdx.x == 0){
    int offs[NE+1]; int o = 0;
    for (int e = 0; e < NE; ++e){ offs[e] = o; o += (int)cnt[e]; }
    offs[NE] = o;
    int nt = 0;
    for (int e = 0; e < NE; ++e){
      int c = (int)cnt[e];
      for (int s = 0; s < c; s += 128)
        desc[nt++] = make_int4(e, offs[e] + s, min(128, c - s), 0);
      off[e] = offs[e]; cur[e] = 0u;
    }
    off[NE] = offs[NE];
    for (int i = nt; i < MAXT; ++i) desc[i] = make_int4(-1, 0, 0, 0);
  }
}

// ---- 5) scatter ----
__global__ void k_scatter(const int* __restrict__ idx, const int* __restrict__ off,
                          u32* __restrict__ cur, int* __restrict__ perm){
  int t = blockIdx.x*256 + threadIdx.x;
  int e = idx[t];
  int pos = off[e] + (int)atomicAdd(&cur[e], 1u);
  perm[pos] = t;
}

// ---- 6) gather x rows -> bf16, fused bias-init of out ----
__global__ void k_gather(const float* __restrict__ x, const int* __restrict__ perm,
                         const int* __restrict__ idx, const float* __restrict__ b2,
                         u16* __restrict__ Xg, float* __restrict__ out){
  int p = blockIdx.x;
  int t = perm[p];
  int e = idx[t];
  const float4* src = (const float4*)(x + (size_t)t*DM);
  float4 v = src[threadIdx.x];
  uint2 o;
  o.x = (u32)f2bf(v.x) | ((u32)f2bf(v.y) << 16);
  o.y = (u32)f2bf(v.z) | ((u32)f2bf(v.w) << 16);
  *(uint2*)(Xg + (size_t)p*DM + threadIdx.x*4) = o;
  float4 bv = ((const float4*)(b2 + (size_t)e*DM))[threadIdx.x];
  ((float4*)(out + (size_t)t*DM))[threadIdx.x] = bv;
}

// ---- 7) transpose+convert weights fp32 [E][R][C] -> bf16 [E][C][R] ----
// write phase: 16B uint4 stores (8 bf16), fully coalesced (128B per 8 lanes)
__global__ void k_trans(const float* __restrict__ in, u16* __restrict__ out,
                        int R, int C){
  __shared__ float tile[64][65];
  int e = blockIdx.z;
  int r0 = blockIdx.x*64, c0 = blockIdx.y*64;
  const float* src = in + ((size_t)e*R + r0)*C + c0;
  int lr = threadIdx.x >> 4, lc = (threadIdx.x & 15) * 4;
#pragma unroll
  for (int i = 0; i < 4; ++i){
    float4 v = *(const float4*)(src + (size_t)(lr + i*16)*C + lc);
    tile[lr + i*16][lc+0] = v.x; tile[lr + i*16][lc+1] = v.y;
    tile[lr + i*16][lc+2] = v.z; tile[lr + i*16][lc+3] = v.w;
  }
  __syncthreads();
  u16* dst = out + ((size_t)e*C + c0)*R + r0;
  int rr = (threadIdx.x & 7) * 8;              // r base (0..56)
  int ocb = threadIdx.x >> 3;                  // 0..31
#pragma unroll
  for (int p = 0; p < 2; ++p){
    int oc = ocb + p*32;                       // output row = original column
    u16 w[8];
#pragma unroll
    for (int k = 0; k < 8; ++k) w[k] = f2bf(tile[rr + k][oc]);
    uint4 o;
    o.x = (u32)w[0] | ((u32)w[1] << 16);
    o.y = (u32)w[2] | ((u32)w[3] << 16);
    o.z = (u32)w[4] | ((u32)w[5] << 16);
    o.w = (u32)w[6] | ((u32)w[7] << 16);
    *(uint4*)(dst + (size_t)oc*R + rr) = o;
  }
}

// ======== m97-structure GEMM, 8 waves (4x2), wave-tile 32x64, BK=32 ========
// Rationale (R7 post-mortem): unified VGPR+AGPR file capped 4-wave acc[4][4]
// kernels at ~3 waves/SIMD (33% occupancy) -> latency exposed. Wave-tile 32x64
// (acc[2][4]=32 AGPR, ~50 VGPR) -> ~6 waves/SIMD, 3 blocks/CU, ~75% occupancy.
// Inner loop identical to proven R2 (stage-next -> ds_read -> MFMA ->
// __syncthreads; no inline asm, compiler-managed waits).

// ---- 8) grouped GEMM 1: H = gelu(Xg @ W1T^T + b1) ----
__global__ __launch_bounds__(512) void k_ffn1(const u16* __restrict__ Xg,
    const u16* __restrict__ W1T, const float* __restrict__ b1,
    u16* __restrict__ H, const int4* __restrict__ desc){
  int pid = blockIdx.x;                        // NWG1 = 2304
  int pid_sw = (pid & 7) * (NWG1/8) + (pid >> 3);
  int ng  = pid_sw / (MAXT*8);                 // n-group 0..3 (L2 ordering, R6)
  int rem = pid_sw - ng*(MAXT*8);
  int mt  = rem >> 3;
  int n0  = (ng*8 + (rem & 7)) * 128;
  int4 dd = desc[mt];
  int e = dd.x; if (e < 0) return;
  int m0 = dd.y, valid = dd.z;
  __shared__ __align__(16) u16 lA[2][128*32];
  __shared__ __align__(16) u16 lB[2][128*32];
  int tid = threadIdx.x, lane = tid & 63, wave = tid >> 6;
  int wr = wave >> 1, wc = wave & 1;           // 4 row-strips x 2 col-strips
  const u16* Bsrc = W1T + ((size_t)e*FF + n0)*DM;
  f32x4 acc[2][4] = {};

  // stage: 512 threads x (1 A-load + 1 B-load) of 16B = full 8KB+8KB tile
  int srow = tid >> 2;                         // 0..127
  int scol = (tid & 3) * 8;                    // 0,8,16,24
  auto stage = [&](int buf, int kt){
    int k0 = kt * 32;
    int ra = m0 + srow; if (ra > TOK-1) ra = TOK-1;
    gld_lds16(Xg   + (size_t)ra  *DM + k0 + scol, &lA[buf][tid*8]);
    gld_lds16(Bsrc + (size_t)srow*DM + k0 + scol, &lB[buf][tid*8]);
  };

  stage(0, 0);
  __syncthreads();
  const int KT = DM / 32;                      // 32
  for (int kt = 0; kt < KT; ++kt){
    int cur = kt & 1;
    if (kt + 1 < KT) stage(cur ^ 1, kt + 1);
    const u16* pa = &lA[cur][(wr*32 + (lane & 15))*32 + (lane >> 4)*8];
    const u16* pb = &lB[cur][(wc*64 + (lane & 15))*32 + (lane >> 4)*8];
    bf16x8 a[2], b[4];
#pragma unroll
    for (int m = 0; m < 2; ++m) a[m] = *(const bf16x8*)(pa + m*16*32);
#pragma unroll
    for (int n = 0; n < 4; ++n) b[n] = *(const bf16x8*)(pb + n*16*32);
#pragma unroll
    for (int m = 0; m < 2; ++m)
#pragma unroll
      for (int n = 0; n < 4; ++n)
        acc[m][n] = __builtin_amdgcn_mfma_f32_16x16x32_bf16(a[m], b[n], acc[m][n], 0, 0, 0);
    __syncthreads();
  }

#pragma unroll
  for (int n = 0; n < 4; ++n){
    int col = n0 + wc*64 + n*16 + (lane & 15);
    float bias = b1[(size_t)e*FF + col];
#pragma unroll
    for (int m = 0; m < 2; ++m){
      int rbase = wr*32 + m*16 + ((lane >> 4) << 2);
#pragma unroll
      for (int j = 0; j < 4; ++j){
        int rit = rbase + j;
        if (rit < valid){
          float v = acc[m][n][j] + bias;
          H[(size_t)(m0 + rit)*FF + col] = f2bf(gelu_f(v));
        }
      }
    }
  }
}

// ---- 9) grouped GEMM 2: out[tok] += H @ W2T^T (split-K=4, atomic f32) ----
__global__ __launch_bounds__(512) void k_ffn2(const u16* __restrict__ H,
    const u16* __restrict__ W2T, float* __restrict__ out,
    const int4* __restrict__ desc, const int* __restrict__ perm){
  int pid = blockIdx.x;                        // NWG2 = 2304
  int pid_sw = (pid & 7) * (NWG2/8) + (pid >> 3);
  int ks  = pid_sw / (MAXT*8);                 // k-split outer (chunk in one stripe)
  int rem = pid_sw - ks*(MAXT*8);
  int mt  = rem >> 3;
  int n0  = (rem & 7) * 128;
  int4 dd = desc[mt];
  int e = dd.x; if (e < 0) return;
  int m0 = dd.y, valid = dd.z;
  __shared__ __align__(16) u16 lA[2][128*32];
  __shared__ __align__(16) u16 lB[2][128*32];
  int tid = threadIdx.x, lane = tid & 63, wave = tid >> 6;
  int wr = wave >> 1, wc = wave & 1;
  const u16* Bsrc = W2T + ((size_t)e*DM + n0)*FF;
  const int kbase = ks * (FF/KS2);             // 1024 elems per split
  f32x4 acc[2][4] = {};

  int srow = tid >> 2;
  int scol = (tid & 3) * 8;
  auto stage = [&](int buf, int kt){
    int k0 = kbase + kt * 32;
    int ra = m0 + srow; if (ra > TOK-1) ra = TOK-1;
    gld_lds16(H    + (size_t)ra  *FF + k0 + scol, &lA[buf][tid*8]);
    gld_lds16(Bsrc + (size_t)srow*FF + k0 + scol, &lB[buf][tid*8]);
  };

  stage(0, 0);
  __syncthreads();
  const int KT = (FF/KS2) / 32;                // 32
  for (int kt = 0; kt < KT; ++kt){
    int cur = kt & 1;
    if (kt + 1 < KT) stage(cur ^ 1, kt + 1);
    const u16* pa = &lA[cur][(wr*32 + (lane & 15))*32 + (lane >> 4)*8];
    const u16* pb = &lB[cur][(wc*64 + (lane & 15))*32 + (lane >> 4)*8];
    bf16x8 a[2], b[4];
#pragma unroll
    for (int m = 0; m < 2; ++m) a[m] = *(const bf16x8*)(pa + m*16*32);
#pragma unroll
    for (int n = 0; n < 4; ++n) b[n] = *(const bf16x8*)(pb + n*16*32);
#pragma unroll
    for (int m = 0; m < 2; ++m)
#pragma unroll
      for (int n = 0; n < 4; ++n)
        acc[m][n] = __builtin_amdgcn_mfma_f32_16x16x32_bf16(a[m], b[n], acc[m][n], 0, 0, 0);
    __syncthreads();
  }

#pragma unroll
  for (int m = 0; m < 2; ++m){
#pragma unroll
    for (int j = 0; j < 4; ++j){
      int rit = wr*32 + m*16 + ((lane >> 4) << 2) + j;
      if (rit < valid){
        int tok = perm[m0 + rit];
#pragma unroll
        for (int n = 0; n < 4; ++n){
          int col = n0 + wc*64 + n*16 + (lane & 15);
          unsafeAtomicAdd(&out[(size_t)tok*DM + col], acc[m][n][j]);
        }
      }
    }
  }
}

extern "C" void kernel_launch(void* const* d_in, const int* in_sizes, int n_in,
                              void* d_out, int out_size, void* d_ws, size_t ws_size,
                              hipStream_t stream){
  const float* x   = (const float*)d_in[0];
  const float* gw  = (const float*)d_in[1];
  const float* gb  = (const float*)d_in[2];
  const float* W1  = (const float*)d_in[3];
  const float* b1  = (const float*)d_in[4];
  const float* W2  = (const float*)d_in[5];
  const float* b2  = (const float*)d_in[6];
  float* out = (float*)d_out;
  char* ws = (char*)d_ws;

  float* logits = (float*)(ws + O_LOGITS);
  float* mArr   = (float*)(ws + O_M);
  float* zArr   = (float*)(ws + O_Z);
  u32*   cnt    = (u32*)  (ws + O_CNT);
  u32*   cur    = (u32*)  (ws + O_CUR);
  int*   off    = (int*)  (ws + O_OFF);
  int4*  desc   = (int4*) (ws + O_DESC);
  int*   perm   = (int*)  (ws + O_PERM);
  int*   idx    = (int*)  (ws + O_IDX);
  u16*   Xg     = (u16*)  (ws + O_XG);
  u16*   W1T    = (u16*)  (ws + O_W1T);
  u16*   W2T    = (u16*)  (ws + O_W2T);
  u16*   Hbuf   = (u16*)  (ws + O_H);

  hipMemsetAsync(ws + O_CNT, 0, 128, stream);   // cnt + cur

  k_gate   <<<TOK/4, 256, 0, stream>>>(x, gw, gb, logits);
  k_lse    <<<32,    256, 0, stream>>>(logits, mArr, zArr);
  k_route  <<<TOK/256, 256, 0, stream>>>(logits, mArr, zArr, cnt, idx);
  k_plan   <<<1,     64,  0, stream>>>(cnt, off, desc, cur);
  k_scatter<<<TOK/256, 256, 0, stream>>>(idx, off, cur, perm);
  k_gather <<<TOK,   256, 0, stream>>>(x, perm, idx, b2, Xg, out);
  k_trans  <<<dim3(DM/64, FF/64, NE), 256, 0, stream>>>(W1, W1T, DM, FF);
  k_trans  <<<dim3(FF/64, DM/64, NE), 256, 0, stream>>>(W2, W2T, FF, DM);
  k_ffn1   <<<NWG1,  512, 0, stream>>>(Xg, W1T, b1, Hbuf, desc);
  k_ffn2   <<<NWG2,  512, 0, stream>>>(Hbuf, W2T, out, desc, perm);
}